// Round 7
// baseline (773.969 us; speedup 1.0000x reference)
//
#include <hip/hip_runtime.h>

// Problem constants
#define B_TOK 32768
#define D_IN  256
#define H1D   512
#define H2D   256
#define NE    16
#define NO    64
#define TK    128            // tokens per block

typedef _Float16 half8 __attribute__((ext_vector_type(8)));
typedef _Float16 half4 __attribute__((ext_vector_type(4)));
typedef float   float4_t __attribute__((ext_vector_type(4)));

// LDS-only barrier: both hazards it protects (h1c publish / h1c WAR) are
// DS-state; global loads stay in flight across it by design.
#define BARRIER_LGKM() do {                                   \
    __builtin_amdgcn_sched_barrier(0);                        \
    asm volatile("s_waitcnt lgkmcnt(0)" ::: "memory");        \
    __builtin_amdgcn_s_barrier();                             \
    __builtin_amdgcn_sched_barrier(0);                        \
  } while (0)

// ---------------------------------------------------------------------------
// Prep kernel (grid 914 x 256):
//  blocks 0..511   : pack x [B][D] fp32 -> fragment-linear fp16 xp (R7 new;
//                    64 tokens/block, LDS transpose, coalesced both sides)
//  blocks 512..639 : W1 [E][D][H1] fp32 -> fragment-linear fp16
//  blocks 640..895 : W2 [E][H1][H2] fp32 -> fragment-linear fp16
//  blocks 896..912 : w3h[e][h2] = W3[e][h2][:].head_w ; c3[e] = b3.head_w
//  block  913      : pack gate_w [D][E] -> 8 B-fragments
// ---------------------------------------------------------------------------
__global__ void prep_kernel(const float* __restrict__ X, const float* __restrict__ W1,
                            const float* __restrict__ W2, const float* __restrict__ W3,
                            const float* __restrict__ b3, const float* __restrict__ hw,
                            const float* __restrict__ gw,
                            _Float16* __restrict__ xp, _Float16* __restrict__ w1p,
                            _Float16* __restrict__ w2p, float* __restrict__ w3h,
                            float* __restrict__ c3, _Float16* __restrict__ gwp) {
  __shared__ _Float16 tile[64 * 260];              // 33,280 B (covers all paths)
  const int blk = blockIdx.x;
  const int tid = threadIdx.x;

  if (blk < 512) {
    // ---- x pack: 64 tokens x 256 D. frag (tok16, kt) at
    //      xp[((tok16*8)+kt)*512 + lane*8], matching the old x_lds layout. --
    const int t0 = blk * 64;
    #pragma unroll
    for (int it = 0; it < 16; ++it) {
      int idx = it * 256 + tid;               // 4096 float4s = 64x256
      int r = idx >> 6, c4 = idx & 63;
      float4_t v = *(const float4_t*)(X + (size_t)(t0 + r) * D_IN + c4 * 4);
      half4 h;
      h[0] = (_Float16)v[0]; h[1] = (_Float16)v[1];
      h[2] = (_Float16)v[2]; h[3] = (_Float16)v[3];
      *(half4*)(tile + r * 260 + c4 * 4) = h;
    }
    __syncthreads();
    const int lane = tid & 63, wv = tid >> 6;
    #pragma unroll
    for (int it = 0; it < 8; ++it) {
      int f = it * 4 + wv;                    // 0..31
      int tt = f >> 3, kt = f & 7;
      half8 v;
      #pragma unroll
      for (int j = 0; j < 8; ++j)
        v[j] = tile[(tt * 16 + (lane & 15)) * 260 + kt * 32 + (lane >> 4) * 8 + j];
      *(half8*)(xp + ((size_t)(((blk * 4 + tt) * 8 + kt) * 64 + lane)) * 8) = v;
    }
  } else if (blk < 640) {
    const int b1i = blk - 512;
    const int e = b1i >> 3, kt = b1i & 7;
    const float* src = W1 + ((size_t)(e * D_IN + kt * 32)) * H1D;
    #pragma unroll
    for (int it = 0; it < 16; ++it) {
      int idx = it * 256 + tid;               // 4096 float4s = 32x512
      int r = idx >> 7, c4 = idx & 127;
      float4_t v = *(const float4_t*)(src + (size_t)r * H1D + c4 * 4);
      half4 h;
      h[0] = (_Float16)v[0]; h[1] = (_Float16)v[1];
      h[2] = (_Float16)v[2]; h[3] = (_Float16)v[3];
      *(half4*)(tile + r * 516 + c4 * 4) = h;
    }
    __syncthreads();
    const int lane = tid & 63, wv = tid >> 6;
    #pragma unroll
    for (int it = 0; it < 8; ++it) {
      int ntg = it * 4 + wv;
      half8 v;
      #pragma unroll
      for (int j = 0; j < 8; ++j)
        v[j] = tile[((lane >> 4) * 8 + j) * 516 + ntg * 16 + (lane & 15)];
      *(half8*)(w1p + ((size_t)(((e * 32 + ntg) * 8 + kt) * 64 + lane)) * 8) = v;
    }
  } else if (blk < 896) {
    const int b2i = blk - 640;
    const int e = b2i >> 4, ktg = b2i & 15;
    const float* src = W2 + ((size_t)(e * H1D + ktg * 32)) * H2D;
    #pragma unroll
    for (int it = 0; it < 8; ++it) {
      int idx = it * 256 + tid;               // 2048 float4s = 32x256
      int r = idx >> 6, c4 = idx & 63;
      float4_t v = *(const float4_t*)(src + (size_t)r * H2D + c4 * 4);
      half4 h;
      h[0] = (_Float16)v[0]; h[1] = (_Float16)v[1];
      h[2] = (_Float16)v[2]; h[3] = (_Float16)v[3];
      *(half4*)(tile + r * 260 + c4 * 4) = h;
    }
    __syncthreads();
    const int lane = tid & 63, wv = tid >> 6;
    #pragma unroll
    for (int it = 0; it < 4; ++it) {
      int ntg = it * 4 + wv;
      half8 v;
      #pragma unroll
      for (int j = 0; j < 8; ++j)
        v[j] = tile[((lane >> 4) * 8 + j) * 260 + ntg * 16 + (lane & 15)];
      *(half8*)(w2p + ((size_t)(((e * 16 + ntg) * 16 + ktg) * 64 + lane)) * 8) = v;
    }
  } else if (blk < 913) {
    int t = (blk - 896) * 256 + tid;
    if (t < NE * H2D) {
      int e = t >> 8, h = t & 255;
      float s = 0.f;
      #pragma unroll
      for (int o = 0; o < NO; ++o) s = fmaf(W3[((size_t)(e * H2D + h)) * NO + o], hw[o], s);
      w3h[t] = s;
    } else if (t < NE * H2D + NE) {
      int e = t - NE * H2D;
      float s = 0.f;
      #pragma unroll
      for (int o = 0; o < NO; ++o) s = fmaf(b3[e * NO + o], hw[o], s);
      c3[e] = s;
    }
  } else {
    for (int t = tid; t < 512; t += 256) {
      int lane = t & 63;
      int kt   = t >> 6;
      int e  = lane & 15;
      int kb = kt * 32 + (lane >> 4) * 8;
      half8 v;
      #pragma unroll
      for (int j = 0; j < 8; ++j)
        v[j] = (_Float16)gw[(kb + j) * NE + e];
      *(half8*)(gwp + (size_t)t * 8) = v;
    }
  }
}

// ---------------------------------------------------------------------------
// Fused main kernel. R7: single-barrier fused phases.
// R0-R6 established: 64 phases x (~5.0k MFMA + ~5.4k fixed overhead) cyc per
// SIMD; overhead is lockstep serial work + sync skew, not drain (R6 null),
// not LDS/L2 BW (R2 null), not load latency (R1/R6 null). Fix: halve the
// phase count. x is evicted from LDS to global fragment-linear xp (prep-
// packed, L3-resident, 8x inter-wave L1 reuse); h1c is DOUBLE-buffered
// (2 x 64 KB); each phase fuses L1 of chunk c with L2 of chunk c-1 and ends
// in ONE lgkm-only barrier. 33 phases x 256 MFMA/wave.
//   phase c: a1 = W1^T(e,ch) @ xp   (c < 32)   [global + global]
//            pack a1 -> h1c[c&1]               [publish at barrier]
//            h2 += h1c[(c-1)&1] @ W2 (c > 0)   [LDS + global]
//            if c even & c>0: epilogue expert (c-2)>>1, rezero h2
//            BARRIER_LGKM
// Hazards: pack(c) writes buf[c&1]; last reader was L2(c-2) in phase c-1,
// separated by that phase's barrier. L2(c) reads buf[c&1] packed in phase c,
// published by its barrier. VGPR budget 256 (2 waves/SIMD); h2+a1+yacc ~160.
// ---------------------------------------------------------------------------
__global__ __launch_bounds__(512, 2) void moe_main(
    const _Float16* __restrict__ xp,
    const float* __restrict__ b1,
    const float* __restrict__ b2,
    const _Float16* __restrict__ w1p,
    const _Float16* __restrict__ w2p,
    const _Float16* __restrict__ gwp,
    const float* __restrict__ gb,
    const float* __restrict__ w3h,
    const float* __restrict__ c3,
    const float* __restrict__ head_b,
    float* __restrict__ out) {
  __shared__ _Float16 h1c[2][64 * 512];            // 2 x 64 KB double buffer
  __shared__ float g_lds[TK * 17];                 // 8,704 B [token][e]
  __shared__ float fin[8 * TK];                    // 4 KB

  const int tid  = threadIdx.x;
  const int w    = tid >> 6;                       // 0..7
  const int lane = tid & 63;
  const int q    = lane >> 4;
  const int l16  = lane & 15;
  const int m0   = blockIdx.x * TK;
  const size_t bt16 = (size_t)blockIdx.x * 8;      // token-tile base

  const float4_t zero4 = (float4_t){0.f, 0.f, 0.f, 0.f};

  // ---- gates via MFMA + shuffle softmax; wave w handles token tile w ------
  {
    float gbv = gb[l16];
    float4_t lg = zero4;
    #pragma unroll
    for (int kt = 0; kt < 8; ++kt) {
      half8 xa = *(const half8*)(xp + ((size_t)((bt16 + w) * 8 + kt)) * 512 + lane * 8);
      half8 bfr = *(const half8*)(gwp + (size_t)kt * 512 + lane * 8);
      lg = __builtin_amdgcn_mfma_f32_16x16x32_f16(xa, bfr, lg, 0, 0, 0);
    }
    #pragma unroll
    for (int r = 0; r < 4; ++r) {
      float v = lg[r] + gbv;                       // logit[token][e=l16]
      float m = v;
      m = fmaxf(m, __shfl_xor(m, 1));
      m = fmaxf(m, __shfl_xor(m, 2));
      m = fmaxf(m, __shfl_xor(m, 4));
      m = fmaxf(m, __shfl_xor(m, 8));
      float p = __expf(v - m);
      float s = p;
      s += __shfl_xor(s, 1);
      s += __shfl_xor(s, 2);
      s += __shfl_xor(s, 4);
      s += __shfl_xor(s, 8);
      g_lds[(w * 16 + q * 4 + r) * 17 + l16] = p / s;
    }
  }
  // g_lds published by the phase barriers before first epilogue read (c=2).

  float yacc[8][4];    // gated accumulator: [mt][r] for token mt*16+q*4+r
  #pragma unroll
  for (int mt = 0; mt < 8; ++mt)
    #pragma unroll
    for (int r = 0; r < 4; ++r) yacc[mt][r] = 0.f;

  float4_t h2[8][2];   // accumulates over the 2 chunks of current expert
  #pragma unroll
  for (int mt = 0; mt < 8; ++mt)
    #pragma unroll
    for (int j = 0; j < 2; ++j) h2[mt][j] = zero4;

  for (int c = 0; c <= 2 * NE; ++c) {
    // ===== L1 of chunk c (c < 32): a1 = W1^T(e,ch) @ xp ====================
    if (c < 2 * NE) {
      const int e = c >> 1, ch = c & 1;
      float4_t a1[2][8];   // [i = col tile][nt = token tile]
      const _Float16* w1e =
          w1p + ((size_t)((e * 32 + ch * 16 + w * 2) * 8)) * 512 + lane * 8;
      const _Float16* xpe = xp + (bt16 * 8) * 512 + lane * 8;
      #pragma unroll
      for (int kt = 0; kt < 8; ++kt) {
        half8 wc[2];
        #pragma unroll
        for (int i = 0; i < 2; ++i)
          wc[i] = *(const half8*)(w1e + (size_t)(i * 8 + kt) * 512);
        half8 xb[8];
        #pragma unroll
        for (int nt = 0; nt < 8; ++nt)
          xb[nt] = *(const half8*)(xpe + (size_t)(nt * 8 + kt) * 512);
        #pragma unroll
        for (int i = 0; i < 2; ++i)
          #pragma unroll
          for (int nt = 0; nt < 8; ++nt)
            a1[i][nt] = __builtin_amdgcn_mfma_f32_16x16x32_f16(
                wc[i], xb[nt], (kt == 0) ? zero4 : a1[i][nt], 0, 0, 0);
      }

      // pack a1 -> h1c[c&1], fragment-linear (R0-verified constants:
      // cc=2w+i -> kt'=w, q'=2i+(q>>1), half-offset (q&1)*4).
      _Float16* hw_ = h1c[c & 1];
      #pragma unroll
      for (int i = 0; i < 2; ++i) {
        int colbase = ch * 256 + (w * 2 + i) * 16 + q * 4;   // global h1 col
        float4_t bb = *(const float4_t*)(b1 + e * H1D + colbase);
        int qp = (i << 1) + (q >> 1);
        int fo = (qp * 16 + l16) * 8 + ((q & 1) << 2);
        #pragma unroll
        for (int nt = 0; nt < 8; ++nt) {
          half4 hv;
          #pragma unroll
          for (int r = 0; r < 4; ++r)
            hv[r] = (_Float16)fmaxf(a1[i][nt][r] + bb[r], 0.f);
          *(half4*)(hw_ + (size_t)(nt * 8 + w) * 512 + fo) = hv;
        }
      }
    }

    // ===== L2 of chunk c-1 (c > 0): h2 += h1c[(c-1)&1] @ W2 ================
    if (c > 0) {
      const int e2 = (c - 1) >> 1, ch2 = (c - 1) & 1;
      const _Float16* hr = h1c[(c - 1) & 1];
      const _Float16* w2e =
          w2p + ((size_t)((e2 * 16 + w * 2) * 16 + ch2 * 8)) * 512 + lane * 8;
      #pragma unroll
      for (int kt = 0; kt < 8; ++kt) {
        half8 w2c[2];
        #pragma unroll
        for (int j = 0; j < 2; ++j)
          w2c[j] = *(const half8*)(w2e + (size_t)(j * 16 + kt) * 512);
        half8 hac[8];
        #pragma unroll
        for (int mt = 0; mt < 8; ++mt)
          hac[mt] = *(const half8*)(hr + (size_t)(mt * 8 + kt) * 512 + lane * 8);
        #pragma unroll
        for (int mt = 0; mt < 8; ++mt)
          #pragma unroll
          for (int j = 0; j < 2; ++j)
            h2[mt][j] = __builtin_amdgcn_mfma_f32_16x16x32_f16(
                hac[mt], w2c[j], h2[mt][j], 0, 0, 0);
      }

      // ---- expert finished at even c: register epilogue + rezero h2 ------
      if ((c & 1) == 0) {
        const int ef = e2;                         // = (c-2)>>1
        float b2v[2], w3v[2];
        #pragma unroll
        for (int j = 0; j < 2; ++j) {
          int n = (w * 2 + j) * 16 + l16;
          b2v[j] = b2[ef * H2D + n];
          w3v[j] = w3h[ef * H2D + n];
        }
        #pragma unroll
        for (int mt = 0; mt < 8; ++mt) {
          #pragma unroll
          for (int r = 0; r < 4; ++r) {
            float s = 0.f;
            #pragma unroll
            for (int j = 0; j < 2; ++j)
              s += fmaxf(h2[mt][j][r] + b2v[j], 0.f) * w3v[j];
            yacc[mt][r] += g_lds[(mt * 16 + q * 4 + r) * 17 + ef] * s;
          }
        }
        #pragma unroll
        for (int mt = 0; mt < 8; ++mt)
          #pragma unroll
          for (int j = 0; j < 2; ++j) h2[mt][j] = zero4;
      }
    }

    BARRIER_LGKM();   // publish h1c[c&1]; retire reads of h1c[(c-1)&1]
  }

  // ---- single final reduction: sum yacc over the 16 l16-lanes (cols) ------
  #pragma unroll
  for (int mt = 0; mt < 8; ++mt) {
    #pragma unroll
    for (int r = 0; r < 4; ++r) {
      float v = yacc[mt][r];
      v += __shfl_xor(v, 1);
      v += __shfl_xor(v, 2);
      v += __shfl_xor(v, 4);
      v += __shfl_xor(v, 8);
      yacc[mt][r] = v;
    }
  }
  if (l16 == 0) {
    #pragma unroll
    for (int mt = 0; mt < 8; ++mt)
      #pragma unroll
      for (int r = 0; r < 4; ++r)
        fin[w * TK + mt * 16 + q * 4 + r] = yacc[mt][r];
  }
  __syncthreads();
  if (tid < TK) {
    float sum = 0.f;
    #pragma unroll
    for (int k = 0; k < 8; ++k) sum += fin[k * TK + tid];
    float gc = 0.f;
    #pragma unroll
    for (int e = 0; e < NE; ++e) gc += g_lds[tid * 17 + e] * c3[e];
    out[m0 + tid] = sum + gc + head_b[0];
  }
}

// ---------------------------------------------------------------------------
extern "C" void kernel_launch(void* const* d_in, const int* in_sizes, int n_in,
                              void* d_out, int out_size, void* d_ws, size_t ws_size,
                              hipStream_t stream) {
  const float* x      = (const float*)d_in[0];
  const float* gate_w = (const float*)d_in[1];
  const float* gate_b = (const float*)d_in[2];
  const float* W1     = (const float*)d_in[3];
  const float* b1     = (const float*)d_in[4];
  const float* W2     = (const float*)d_in[5];
  const float* b2     = (const float*)d_in[6];
  const float* W3     = (const float*)d_in[7];
  const float* b3     = (const float*)d_in[8];
  const float* head_w = (const float*)d_in[9];
  const float* head_b = (const float*)d_in[10];
  float* out = (float*)d_out;

  // workspace layout (16B-aligned); total 25,190,464 B
  char* ws = (char*)d_ws;
  _Float16* w1p = (_Float16*)(ws);                 // 4,194,304 B
  _Float16* w2p = (_Float16*)(ws + 4194304);       // 4,194,304 B
  _Float16* gwp = (_Float16*)(ws + 8388608);       // 8,192 B
  float*    w3h = (float*)(ws + 8396800);          // 16,384 B
  float*    c3  = (float*)(ws + 8413184);          // 64 B
  _Float16* xp  = (_Float16*)(ws + 8413248);       // 16,777,216 B

  hipLaunchKernelGGL(prep_kernel, dim3(914), dim3(256), 0, stream,
                     x, W1, W2, W3, b3, head_w, gate_w, xp, w1p, w2p, w3h, c3, gwp);
  hipLaunchKernelGGL(moe_main, dim3(B_TOK / TK), dim3(512), 0, stream,
                     xp, b1, b2, w1p, w2p, gwp, gate_b, w3h, c3, head_b, out);
}

// Round 8
// 497.929 us; speedup vs baseline: 1.5544x; 1.5544x over previous
//
#include <hip/hip_runtime.h>

// Problem constants
#define B_TOK 32768
#define D_IN  256
#define H1D   512
#define H2D   256
#define NE    16
#define NO    64
#define TK    64             // tokens per block (2 blocks/CU target)

typedef _Float16 half8 __attribute__((ext_vector_type(8)));
typedef _Float16 half4 __attribute__((ext_vector_type(4)));
typedef float   float4_t __attribute__((ext_vector_type(4)));

// ---------------------------------------------------------------------------
// Prep kernel (grid 402 x 256), coalesced-read version (R1, kept):
//  blocks 0..127   : W1 [E][D][H1] fp32 -> fragment-linear fp16 (LDS transpose)
//  blocks 128..383 : W2 [E][H1][H2] fp32 -> fragment-linear fp16 (LDS transpose)
//  blocks 384..400 : w3h[e][h2] = W3[e][h2][:].head_w ; c3[e] = b3[e][:].head_w
//  block  401      : pack gate_w [D][E] -> 8 B-fragments
// ---------------------------------------------------------------------------
__global__ void prep_kernel(const float* __restrict__ W1, const float* __restrict__ W2,
                            const float* __restrict__ W3, const float* __restrict__ b3,
                            const float* __restrict__ hw, const float* __restrict__ gw,
                            _Float16* __restrict__ w1p, _Float16* __restrict__ w2p,
                            float* __restrict__ w3h, float* __restrict__ c3,
                            _Float16* __restrict__ gwp) {
  __shared__ _Float16 tile[32 * 516];
  const int blk = blockIdx.x;
  const int tid = threadIdx.x;

  if (blk < 128) {
    const int e = blk >> 3, kt = blk & 7;
    const float* src = W1 + ((size_t)(e * D_IN + kt * 32)) * H1D;
    #pragma unroll
    for (int it = 0; it < 16; ++it) {
      int idx = it * 256 + tid;               // 4096 float4s = 32x512
      int r = idx >> 7, c4 = idx & 127;
      float4_t v = *(const float4_t*)(src + (size_t)r * H1D + c4 * 4);
      half4 h;
      h[0] = (_Float16)v[0]; h[1] = (_Float16)v[1];
      h[2] = (_Float16)v[2]; h[3] = (_Float16)v[3];
      *(half4*)(tile + r * 516 + c4 * 4) = h;
    }
    __syncthreads();
    const int lane = tid & 63, wv = tid >> 6;
    #pragma unroll
    for (int it = 0; it < 8; ++it) {
      int ntg = it * 4 + wv;
      half8 v;
      #pragma unroll
      for (int j = 0; j < 8; ++j)
        v[j] = tile[((lane >> 4) * 8 + j) * 516 + ntg * 16 + (lane & 15)];
      *(half8*)(w1p + ((size_t)(((e * 32 + ntg) * 8 + kt) * 64 + lane)) * 8) = v;
    }
  } else if (blk < 384) {
    const int b2i = blk - 128;
    const int e = b2i >> 4, ktg = b2i & 15;
    const float* src = W2 + ((size_t)(e * H1D + ktg * 32)) * H2D;
    #pragma unroll
    for (int it = 0; it < 8; ++it) {
      int idx = it * 256 + tid;               // 2048 float4s = 32x256
      int r = idx >> 6, c4 = idx & 63;
      float4_t v = *(const float4_t*)(src + (size_t)r * H2D + c4 * 4);
      half4 h;
      h[0] = (_Float16)v[0]; h[1] = (_Float16)v[1];
      h[2] = (_Float16)v[2]; h[3] = (_Float16)v[3];
      *(half4*)(tile + r * 260 + c4 * 4) = h;
    }
    __syncthreads();
    const int lane = tid & 63, wv = tid >> 6;
    #pragma unroll
    for (int it = 0; it < 4; ++it) {
      int ntg = it * 4 + wv;
      half8 v;
      #pragma unroll
      for (int j = 0; j < 8; ++j)
        v[j] = tile[((lane >> 4) * 8 + j) * 260 + ntg * 16 + (lane & 15)];
      *(half8*)(w2p + ((size_t)(((e * 16 + ntg) * 16 + ktg) * 64 + lane)) * 8) = v;
    }
  } else if (blk < 401) {
    int t = (blk - 384) * 256 + tid;
    if (t < NE * H2D) {
      int e = t >> 8, h = t & 255;
      float s = 0.f;
      #pragma unroll
      for (int o = 0; o < NO; ++o) s = fmaf(W3[((size_t)(e * H2D + h)) * NO + o], hw[o], s);
      w3h[t] = s;
    } else if (t < NE * H2D + NE) {
      int e = t - NE * H2D;
      float s = 0.f;
      #pragma unroll
      for (int o = 0; o < NO; ++o) s = fmaf(b3[e * NO + o], hw[o], s);
      c3[e] = s;
    }
  } else {
    for (int t = tid; t < 512; t += 256) {
      int lane = t & 63;
      int kt   = t >> 6;
      int e  = lane & 15;
      int kb = kt * 32 + (lane >> 4) * 8;
      half8 v;
      #pragma unroll
      for (int j = 0; j < 8; ++j)
        v[j] = (_Float16)gw[(kb + j) * NE + e];
      *(half8*)(gwp + (size_t)t * 8) = v;
    }
  }
}

// ---------------------------------------------------------------------------
// Fused main kernel. R8: the R5 kernel body (TK=64, 8 waves, 72 KB LDS,
// VGPR~72, passed at 434 us) with EXACTLY ONE change: occupancy attributes.
//
// Occupancy forensics across R0-R7: per-SIMD VGPR pool = 512.
//   R3 (512,4): VGPR 64,  LDS 72K -> Occupancy 44.7% (2 blocks/CU)
//   R5 (512,2): VGPR 72,  LDS 72K -> Occupancy 23.4% (1 block/CU)  [!]
// Same LDS, same grid, resources permit 2 blocks in both -> the
// __launch_bounds__ 2nd arg acts as a waves/EU CAP on this toolchain.
// Every "lockstep" kernel so far ran artificially capped at 8 waves/CU.
// R8 lifts the cap without the R3/R4 spill pathology:
//   __launch_bounds__(512) + amdgpu_waves_per_eu(2,4)
// (min 2 -> regalloc relaxed, no forced 64-reg target; max 4 -> 16 waves/CU
// = 2 independent barrier domains; one domain's MFMA covers the other's
// pack/epilogue/barrier skew.)
//
// Per expert, per 256-col chunk (16 col-tiles, 4 token-tiles):
//   L1ch: wave w -> col-tiles {2w,2w+1} x all 4 token-tiles
//         (A=W1^T frags global, B=x frags LDS) -> frag-linear h1c -> barrier
//   L2ch: wave w -> h2col-tiles {2w,2w+1} x all 4 token-tiles
//         (A=h1c frags LDS, B=W2 frags global), accumulate -> barrier (WAR)
// Pack uses the R0-verified constants: cc=2w+i -> kt'=w, q'=2i+(q>>1).
// ---------------------------------------------------------------------------
__global__ __launch_bounds__(512)
__attribute__((amdgpu_waves_per_eu(2, 4)))
void moe_main(
    const float* __restrict__ x,
    const float* __restrict__ b1,
    const float* __restrict__ b2,
    const _Float16* __restrict__ w1p,
    const _Float16* __restrict__ w2p,
    const _Float16* __restrict__ gwp,
    const float* __restrict__ gb,
    const float* __restrict__ w3h,
    const float* __restrict__ c3,
    const float* __restrict__ head_b,
    float* __restrict__ out) {
  __shared__ _Float16 x_lds[32 * 512];             // 32 KB fragment-linear
  __shared__ _Float16 h1c[32 * 512];               // 32 KB fragment-linear chunk
  __shared__ float g_lds[TK * 17];                 // 4,352 B [token][e]
  __shared__ float fin[8 * TK];                    // 2 KB

  const int tid  = threadIdx.x;
  const int w    = tid >> 6;                       // 0..7
  const int lane = tid & 63;
  const int q    = lane >> 4;
  const int l16  = lane & 15;
  const int m0   = blockIdx.x * TK;

  const float4_t zero4 = (float4_t){0.f, 0.f, 0.f, 0.f};

  // ---- stage x tile into LDS as MFMA A-fragments: frag (nt,kt) at
  //      x_lds[(nt*8+kt)*512 + lane*8]. Wave w: token tile (w&3),
  //      k-frags (w>>2)*4 .. +3. --------------------------------------------
  {
    const int tt = w & 3, fb = (w >> 2) * 4;
    #pragma unroll
    for (int f = 0; f < 4; ++f) {
      const int kt = fb + f;
      const float* xr = x + (size_t)(m0 + tt * 16 + l16) * D_IN + kt * 32 + q * 8;
      float4_t v0 = *(const float4_t*)(xr);
      float4_t v1 = *(const float4_t*)(xr + 4);
      half8 h;
      h[0] = (_Float16)v0[0]; h[1] = (_Float16)v0[1];
      h[2] = (_Float16)v0[2]; h[3] = (_Float16)v0[3];
      h[4] = (_Float16)v1[0]; h[5] = (_Float16)v1[1];
      h[6] = (_Float16)v1[2]; h[7] = (_Float16)v1[3];
      *(half8*)(x_lds + (size_t)(tt * 8 + kt) * 512 + lane * 8) = h;
    }
  }
  __syncthreads();   // x_lds ready

  // ---- gates via MFMA + shuffle softmax; waves 0..3, token tile w ---------
  if (w < 4) {
    float gbv = gb[l16];
    float4_t lg = zero4;
    #pragma unroll
    for (int kt = 0; kt < 8; ++kt) {
      half8 xa = *(const half8*)(x_lds + (size_t)(w * 8 + kt) * 512 + lane * 8);
      half8 bfr = *(const half8*)(gwp + (size_t)kt * 512 + lane * 8);
      lg = __builtin_amdgcn_mfma_f32_16x16x32_f16(xa, bfr, lg, 0, 0, 0);
    }
    #pragma unroll
    for (int r = 0; r < 4; ++r) {
      float v = lg[r] + gbv;                       // logit[token][e=l16]
      float m = v;
      m = fmaxf(m, __shfl_xor(m, 1));
      m = fmaxf(m, __shfl_xor(m, 2));
      m = fmaxf(m, __shfl_xor(m, 4));
      m = fmaxf(m, __shfl_xor(m, 8));
      float p = __expf(v - m);
      float s = p;
      s += __shfl_xor(s, 1);
      s += __shfl_xor(s, 2);
      s += __shfl_xor(s, 4);
      s += __shfl_xor(s, 8);
      g_lds[(w * 16 + q * 4 + r) * 17 + l16] = p / s;
    }
  }
  // g_lds becomes visible via in-loop barriers before first epilogue read.

  float yacc[4][4];    // gated accumulator: [nt][r] for token nt*16+q*4+r
  #pragma unroll
  for (int nt = 0; nt < 4; ++nt)
    #pragma unroll
    for (int r = 0; r < 4; ++r) yacc[nt][r] = 0.f;

  for (int e = 0; e < NE; ++e) {
    float4_t h2[4][2];   // [token tile nt][h2col tile j]; first write at
                         // ch==0,kt==0 via zero-acc MFMA (statically unrolled)

    #pragma unroll
    for (int ch = 0; ch < 2; ++ch) {
      // ===== L1 chunk: wave w -> chunk col-tiles {2w,2w+1} x 4 tok-tiles ===
      float4_t a1[2][4];   // [i = col tile][nt = token tile]

      const _Float16* w1e =
          w1p + ((size_t)((e * 32 + ch * 16 + w * 2) * 8)) * 512 + lane * 8;
      #pragma unroll
      for (int kt = 0; kt < 8; ++kt) {
        half8 wc[2];
        #pragma unroll
        for (int i = 0; i < 2; ++i)
          wc[i] = *(const half8*)(w1e + (size_t)(i * 8 + kt) * 512);
        half8 xb[4];
        #pragma unroll
        for (int nt = 0; nt < 4; ++nt)
          xb[nt] = *(const half8*)(x_lds + (size_t)(nt * 8 + kt) * 512 + lane * 8);
        #pragma unroll
        for (int i = 0; i < 2; ++i)
          #pragma unroll
          for (int nt = 0; nt < 4; ++nt)
            a1[i][nt] = __builtin_amdgcn_mfma_f32_16x16x32_f16(
                wc[i], xb[nt], (kt == 0) ? zero4 : a1[i][nt], 0, 0, 0);
      }

      // bias + relu + store into FRAGMENT-LINEAR chunk layout.
      // a1[i][nt][r] = h1[tok = nt*16+l16][chunk col = (2w+i)*16 + q*4 + r].
      // cc=2w+i -> chunk k-tile kt'=w; lane' q' = 2i+(q>>1);
      // half-offset (q&1)*4 + r. (R0-verified constants.)
      #pragma unroll
      for (int i = 0; i < 2; ++i) {
        int colbase = ch * 256 + (w * 2 + i) * 16 + q * 4;   // global h1 col
        float4_t bb = *(const float4_t*)(b1 + e * H1D + colbase);
        int qp = (i << 1) + (q >> 1);
        int fo = (qp * 16 + l16) * 8 + ((q & 1) << 2);
        #pragma unroll
        for (int nt = 0; nt < 4; ++nt) {
          half4 hv;
          #pragma unroll
          for (int r = 0; r < 4; ++r)
            hv[r] = (_Float16)fmaxf(a1[i][nt][r] + bb[r], 0.f);
          *(half4*)(h1c + (size_t)(nt * 8 + w) * 512 + fo) = hv;
        }
      }

      __syncthreads();   // h1 chunk ready

      // ===== L2 partial: wave w -> h2col-tiles {2w,2w+1} x 4 tok-tiles =====
      const _Float16* w2e =
          w2p + ((size_t)((e * 16 + w * 2) * 16 + ch * 8)) * 512 + lane * 8;
      #pragma unroll
      for (int kt = 0; kt < 8; ++kt) {
        half8 w2c[2];
        #pragma unroll
        for (int j = 0; j < 2; ++j)
          w2c[j] = *(const half8*)(w2e + (size_t)(j * 16 + kt) * 512);
        half8 hac[4];
        #pragma unroll
        for (int nt = 0; nt < 4; ++nt)
          hac[nt] = *(const half8*)(h1c + (size_t)(nt * 8 + kt) * 512 + lane * 8);
        #pragma unroll
        for (int nt = 0; nt < 4; ++nt)
          #pragma unroll
          for (int j = 0; j < 2; ++j)
            h2[nt][j] = __builtin_amdgcn_mfma_f32_16x16x32_f16(
                hac[nt], w2c[j],
                (ch == 0 && kt == 0) ? zero4 : h2[nt][j], 0, 0, 0);
      }

      __syncthreads();   // WAR: h1c reads done before next chunk/expert L1
    }

    // ---- register epilogue: relu(h2+b2).w3h, gate folded, accumulate ------
    // h2[nt][j][r] = h2[tok=nt*16+q*4+r][h2col=(2w+j)*16+l16]
    float b2v[2], w3v[2];
    #pragma unroll
    for (int j = 0; j < 2; ++j) {
      int n = (w * 2 + j) * 16 + l16;
      b2v[j] = b2[e * H2D + n];
      w3v[j] = w3h[e * H2D + n];
    }
    #pragma unroll
    for (int nt = 0; nt < 4; ++nt) {
      #pragma unroll
      for (int r = 0; r < 4; ++r) {
        float s = 0.f;
        #pragma unroll
        for (int j = 0; j < 2; ++j)
          s += fmaxf(h2[nt][j][r] + b2v[j], 0.f) * w3v[j];
        yacc[nt][r] += g_lds[(nt * 16 + q * 4 + r) * 17 + e] * s;
      }
    }
  }

  // ---- final reduction: sum yacc over the 16 l16-lanes (h2col within
  //      tile), then over the 8 waves via fin[8][TK] -----------------------
  #pragma unroll
  for (int nt = 0; nt < 4; ++nt) {
    #pragma unroll
    for (int r = 0; r < 4; ++r) {
      float v = yacc[nt][r];
      v += __shfl_xor(v, 1);
      v += __shfl_xor(v, 2);
      v += __shfl_xor(v, 4);
      v += __shfl_xor(v, 8);
      yacc[nt][r] = v;
    }
  }
  if (l16 == 0) {
    #pragma unroll
    for (int nt = 0; nt < 4; ++nt)
      #pragma unroll
      for (int r = 0; r < 4; ++r)
        fin[w * TK + nt * 16 + q * 4 + r] = yacc[nt][r];
  }
  __syncthreads();
  if (tid < TK) {
    float sum = 0.f;
    #pragma unroll
    for (int k = 0; k < 8; ++k) sum += fin[k * TK + tid];
    float gc = 0.f;
    #pragma unroll
    for (int e = 0; e < NE; ++e) gc += g_lds[tid * 17 + e] * c3[e];
    out[m0 + tid] = sum + gc + head_b[0];
  }
}

// ---------------------------------------------------------------------------
extern "C" void kernel_launch(void* const* d_in, const int* in_sizes, int n_in,
                              void* d_out, int out_size, void* d_ws, size_t ws_size,
                              hipStream_t stream) {
  const float* x      = (const float*)d_in[0];
  const float* gate_w = (const float*)d_in[1];
  const float* gate_b = (const float*)d_in[2];
  const float* W1     = (const float*)d_in[3];
  const float* b1     = (const float*)d_in[4];
  const float* W2     = (const float*)d_in[5];
  const float* b2     = (const float*)d_in[6];
  const float* W3     = (const float*)d_in[7];
  const float* b3     = (const float*)d_in[8];
  const float* head_w = (const float*)d_in[9];
  const float* head_b = (const float*)d_in[10];
  float* out = (float*)d_out;

  // workspace layout (16B-aligned)
  char* ws = (char*)d_ws;
  _Float16* w1p = (_Float16*)(ws);                 // 4,194,304 B
  _Float16* w2p = (_Float16*)(ws + 4194304);       // 4,194,304 B
  _Float16* gwp = (_Float16*)(ws + 8388608);       // 8,192 B
  float*    w3h = (float*)(ws + 8396800);          // 16,384 B
  float*    c3  = (float*)(ws + 8413184);          // 64 B

  hipLaunchKernelGGL(prep_kernel, dim3(402), dim3(256), 0, stream,
                     W1, W2, W3, b3, head_w, gate_w, w1p, w2p, w3h, c3, gwp);
  hipLaunchKernelGGL(moe_main, dim3(B_TOK / TK), dim3(512), 0, stream,
                     x, b1, b2, w1p, w2p, gwp, gate_b, w3h, c3, head_b, out);
}

// Round 9
// 393.584 us; speedup vs baseline: 1.9665x; 1.2651x over previous
//
#include <hip/hip_runtime.h>

// Problem constants
#define B_TOK 32768
#define D_IN  256
#define H1D   512
#define H2D   256
#define NE    16
#define NO    64
#define TK    64             // tokens per block (2 blocks/CU target)

typedef _Float16 half8 __attribute__((ext_vector_type(8)));
typedef _Float16 half4 __attribute__((ext_vector_type(4)));
typedef float   float4_t __attribute__((ext_vector_type(4)));

// ---------------------------------------------------------------------------
// Prep kernel (grid 402 x 256), coalesced-read version (R1, kept):
//  blocks 0..127   : W1 [E][D][H1] fp32 -> fragment-linear fp16 (LDS transpose)
//  blocks 128..383 : W2 [E][H1][H2] fp32 -> fragment-linear fp16 (LDS transpose)
//  blocks 384..400 : w3h[e][h2] = W3[e][h2][:].head_w ; c3[e] = b3[e][:].head_w
//  block  401      : pack gate_w [D][E] -> 8 B-fragments
// ---------------------------------------------------------------------------
__global__ void prep_kernel(const float* __restrict__ W1, const float* __restrict__ W2,
                            const float* __restrict__ W3, const float* __restrict__ b3,
                            const float* __restrict__ hw, const float* __restrict__ gw,
                            _Float16* __restrict__ w1p, _Float16* __restrict__ w2p,
                            float* __restrict__ w3h, float* __restrict__ c3,
                            _Float16* __restrict__ gwp) {
  __shared__ _Float16 tile[32 * 516];
  const int blk = blockIdx.x;
  const int tid = threadIdx.x;

  if (blk < 128) {
    const int e = blk >> 3, kt = blk & 7;
    const float* src = W1 + ((size_t)(e * D_IN + kt * 32)) * H1D;
    #pragma unroll
    for (int it = 0; it < 16; ++it) {
      int idx = it * 256 + tid;               // 4096 float4s = 32x512
      int r = idx >> 7, c4 = idx & 127;
      float4_t v = *(const float4_t*)(src + (size_t)r * H1D + c4 * 4);
      half4 h;
      h[0] = (_Float16)v[0]; h[1] = (_Float16)v[1];
      h[2] = (_Float16)v[2]; h[3] = (_Float16)v[3];
      *(half4*)(tile + r * 516 + c4 * 4) = h;
    }
    __syncthreads();
    const int lane = tid & 63, wv = tid >> 6;
    #pragma unroll
    for (int it = 0; it < 8; ++it) {
      int ntg = it * 4 + wv;
      half8 v;
      #pragma unroll
      for (int j = 0; j < 8; ++j)
        v[j] = tile[((lane >> 4) * 8 + j) * 516 + ntg * 16 + (lane & 15)];
      *(half8*)(w1p + ((size_t)(((e * 32 + ntg) * 8 + kt) * 64 + lane)) * 8) = v;
    }
  } else if (blk < 384) {
    const int b2i = blk - 128;
    const int e = b2i >> 4, ktg = b2i & 15;
    const float* src = W2 + ((size_t)(e * H1D + ktg * 32)) * H2D;
    #pragma unroll
    for (int it = 0; it < 8; ++it) {
      int idx = it * 256 + tid;               // 2048 float4s = 32x256
      int r = idx >> 6, c4 = idx & 63;
      float4_t v = *(const float4_t*)(src + (size_t)r * H2D + c4 * 4);
      half4 h;
      h[0] = (_Float16)v[0]; h[1] = (_Float16)v[1];
      h[2] = (_Float16)v[2]; h[3] = (_Float16)v[3];
      *(half4*)(tile + r * 260 + c4 * 4) = h;
    }
    __syncthreads();
    const int lane = tid & 63, wv = tid >> 6;
    #pragma unroll
    for (int it = 0; it < 4; ++it) {
      int ntg = it * 4 + wv;
      half8 v;
      #pragma unroll
      for (int j = 0; j < 8; ++j)
        v[j] = tile[((lane >> 4) * 8 + j) * 260 + ntg * 16 + (lane & 15)];
      *(half8*)(w2p + ((size_t)(((e * 16 + ntg) * 16 + ktg) * 64 + lane)) * 8) = v;
    }
  } else if (blk < 401) {
    int t = (blk - 384) * 256 + tid;
    if (t < NE * H2D) {
      int e = t >> 8, h = t & 255;
      float s = 0.f;
      #pragma unroll
      for (int o = 0; o < NO; ++o) s = fmaf(W3[((size_t)(e * H2D + h)) * NO + o], hw[o], s);
      w3h[t] = s;
    } else if (t < NE * H2D + NE) {
      int e = t - NE * H2D;
      float s = 0.f;
      #pragma unroll
      for (int o = 0; o < NO; ++o) s = fmaf(b3[e * NO + o], hw[o], s);
      c3[e] = s;
    }
  } else {
    for (int t = tid; t < 512; t += 256) {
      int lane = t & 63;
      int kt   = t >> 6;
      int e  = lane & 15;
      int kb = kt * 32 + (lane >> 4) * 8;
      half8 v;
      #pragma unroll
      for (int j = 0; j < 8; ++j)
        v[j] = (_Float16)gw[(kb + j) * NE + e];
      *(half8*)(gwp + (size_t)t * 8) = v;
    }
  }
}

// ---------------------------------------------------------------------------
// Fused main kernel. R9: TK=64 body trimmed to fit the 64-arch-VGPR tier
// WITHOUT spills, compiled with __launch_bounds__(512,4) — the combination
// R0-R8 forensics says gives 2 blocks/CU (2 independent barrier domains).
//
// Dispatch-resource rule inferred from R0-R8: blocks/CU is charged
// arch VGPR + accum (AGPR) regs; MFMA accumulators land in the accum half,
// so total/wave ~ arch + 64. arch=64 -> total 128 -> 4 waves/SIMD -> 2
// blocks (R3: occ 44.7%); arch=72 -> 1 block (R5/R8: occ 23%). R3 overshot
// the 128-total tier by only a few regs (spill ~15 B/thread/phase, WRITE
// 129 MB). R9 register surgery to fit cleanly:
//   - L1 token-split: nt in {0,1} then {2,3}, a1[2][2] (peak 32 -> 16;
//     W1 frags re-read second half, L1-cache-hot)
//   - L2 inner token-split: hac[2] per half (16 -> 8)
//   - zero-acc first MFMA (no init ops; h2 liveness starts at use)
//
// Per expert, per 256-col chunk (16 col-tiles, 4 token-tiles):
//   L1ch: wave w -> col-tiles {2w,2w+1} x 4 tok-tiles (in 2 nt-halves)
//         (A=W1^T frags global, B=x frags LDS) -> frag-linear h1c -> barrier
//   L2ch: wave w -> h2col-tiles {2w,2w+1} x 4 tok-tiles
//         (A=h1c frags LDS, B=W2 frags global), accumulate -> barrier (WAR)
// Pack uses the R0-verified constants: cc=2w+i -> kt'=w, q'=2i+(q>>1).
// ---------------------------------------------------------------------------
__global__ __launch_bounds__(512, 4) void moe_main(
    const float* __restrict__ x,
    const float* __restrict__ b1,
    const float* __restrict__ b2,
    const _Float16* __restrict__ w1p,
    const _Float16* __restrict__ w2p,
    const _Float16* __restrict__ gwp,
    const float* __restrict__ gb,
    const float* __restrict__ w3h,
    const float* __restrict__ c3,
    const float* __restrict__ head_b,
    float* __restrict__ out) {
  __shared__ _Float16 x_lds[32 * 512];             // 32 KB fragment-linear
  __shared__ _Float16 h1c[32 * 512];               // 32 KB fragment-linear chunk
  __shared__ float g_lds[TK * 17];                 // 4,352 B [token][e]
  __shared__ float fin[8 * TK];                    // 2 KB

  const int tid  = threadIdx.x;
  const int w    = tid >> 6;                       // 0..7
  const int lane = tid & 63;
  const int q    = lane >> 4;
  const int l16  = lane & 15;
  const int m0   = blockIdx.x * TK;

  const float4_t zero4 = (float4_t){0.f, 0.f, 0.f, 0.f};

  // ---- stage x tile into LDS as MFMA A-fragments: frag (nt,kt) at
  //      x_lds[(nt*8+kt)*512 + lane*8]. Wave w: token tile (w&3),
  //      k-frags (w>>2)*4 .. +3. --------------------------------------------
  {
    const int tt = w & 3, fb = (w >> 2) * 4;
    #pragma unroll
    for (int f = 0; f < 4; ++f) {
      const int kt = fb + f;
      const float* xr = x + (size_t)(m0 + tt * 16 + l16) * D_IN + kt * 32 + q * 8;
      float4_t v0 = *(const float4_t*)(xr);
      float4_t v1 = *(const float4_t*)(xr + 4);
      half8 h;
      h[0] = (_Float16)v0[0]; h[1] = (_Float16)v0[1];
      h[2] = (_Float16)v0[2]; h[3] = (_Float16)v0[3];
      h[4] = (_Float16)v1[0]; h[5] = (_Float16)v1[1];
      h[6] = (_Float16)v1[2]; h[7] = (_Float16)v1[3];
      *(half8*)(x_lds + (size_t)(tt * 8 + kt) * 512 + lane * 8) = h;
    }
  }
  __syncthreads();   // x_lds ready

  // ---- gates via MFMA + shuffle softmax; waves 0..3, token tile w ---------
  if (w < 4) {
    float gbv = gb[l16];
    float4_t lg = zero4;
    #pragma unroll
    for (int kt = 0; kt < 8; ++kt) {
      half8 xa = *(const half8*)(x_lds + (size_t)(w * 8 + kt) * 512 + lane * 8);
      half8 bfr = *(const half8*)(gwp + (size_t)kt * 512 + lane * 8);
      lg = __builtin_amdgcn_mfma_f32_16x16x32_f16(xa, bfr, lg, 0, 0, 0);
    }
    #pragma unroll
    for (int r = 0; r < 4; ++r) {
      float v = lg[r] + gbv;                       // logit[token][e=l16]
      float m = v;
      m = fmaxf(m, __shfl_xor(m, 1));
      m = fmaxf(m, __shfl_xor(m, 2));
      m = fmaxf(m, __shfl_xor(m, 4));
      m = fmaxf(m, __shfl_xor(m, 8));
      float p = __expf(v - m);
      float s = p;
      s += __shfl_xor(s, 1);
      s += __shfl_xor(s, 2);
      s += __shfl_xor(s, 4);
      s += __shfl_xor(s, 8);
      g_lds[(w * 16 + q * 4 + r) * 17 + l16] = p / s;
    }
  }
  // g_lds becomes visible via in-loop barriers before first epilogue read.

  float yacc[4][4];    // gated accumulator: [nt][r] for token nt*16+q*4+r
  #pragma unroll
  for (int nt = 0; nt < 4; ++nt)
    #pragma unroll
    for (int r = 0; r < 4; ++r) yacc[nt][r] = 0.f;

  for (int e = 0; e < NE; ++e) {
    float4_t h2[4][2];   // [token tile nt][h2col tile j]; first write at
                         // ch==0,kt==0 via zero-acc MFMA (statically unrolled)

    #pragma unroll
    for (int ch = 0; ch < 2; ++ch) {
      const _Float16* w1e =
          w1p + ((size_t)((e * 32 + ch * 16 + w * 2) * 8)) * 512 + lane * 8;

      // ===== L1 chunk, token-split into two nt-halves (a1 peak = 16 regs).
      //       W1 frags re-read in the 2nd half (L1-cache-hot). =============
      #pragma unroll
      for (int half = 0; half < 2; ++half) {
        float4_t a1[2][2];   // [i = col tile][n2 = token tile within half]
        #pragma unroll
        for (int kt = 0; kt < 8; ++kt) {
          half8 wc[2];
          #pragma unroll
          for (int i = 0; i < 2; ++i)
            wc[i] = *(const half8*)(w1e + (size_t)(i * 8 + kt) * 512);
          half8 xb[2];
          #pragma unroll
          for (int n2 = 0; n2 < 2; ++n2)
            xb[n2] = *(const half8*)(
                x_lds + (size_t)((half * 2 + n2) * 8 + kt) * 512 + lane * 8);
          #pragma unroll
          for (int i = 0; i < 2; ++i)
            #pragma unroll
            for (int n2 = 0; n2 < 2; ++n2)
              a1[i][n2] = __builtin_amdgcn_mfma_f32_16x16x32_f16(
                  wc[i], xb[n2], (kt == 0) ? zero4 : a1[i][n2], 0, 0, 0);
        }

        // bias + relu + store into FRAGMENT-LINEAR chunk layout.
        // a1[i][n2][r] = h1[tok=(2*half+n2)*16+l16][col=(2w+i)*16+q*4+r].
        // cc=2w+i -> chunk k-tile kt'=w; lane' q'=2i+(q>>1);
        // half-offset (q&1)*4 + r. (R0-verified constants.)
        #pragma unroll
        for (int i = 0; i < 2; ++i) {
          int colbase = ch * 256 + (w * 2 + i) * 16 + q * 4;   // global h1 col
          float4_t bb = *(const float4_t*)(b1 + e * H1D + colbase);
          int qp = (i << 1) + (q >> 1);
          int fo = (qp * 16 + l16) * 8 + ((q & 1) << 2);
          #pragma unroll
          for (int n2 = 0; n2 < 2; ++n2) {
            int nt = half * 2 + n2;
            half4 hv;
            #pragma unroll
            for (int r = 0; r < 4; ++r)
              hv[r] = (_Float16)fmaxf(a1[i][n2][r] + bb[r], 0.f);
            *(half4*)(h1c + (size_t)(nt * 8 + w) * 512 + fo) = hv;
          }
        }
      }

      __syncthreads();   // h1 chunk ready

      // ===== L2 partial: wave w -> h2col-tiles {2w,2w+1} x 4 tok-tiles,
      //       inner token-split (hac peak = 8 regs) ========================
      const _Float16* w2e =
          w2p + ((size_t)((e * 16 + w * 2) * 16 + ch * 8)) * 512 + lane * 8;
      #pragma unroll
      for (int kt = 0; kt < 8; ++kt) {
        half8 w2c[2];
        #pragma unroll
        for (int j = 0; j < 2; ++j)
          w2c[j] = *(const half8*)(w2e + (size_t)(j * 16 + kt) * 512);
        #pragma unroll
        for (int half = 0; half < 2; ++half) {
          half8 hac[2];
          #pragma unroll
          for (int n2 = 0; n2 < 2; ++n2)
            hac[n2] = *(const half8*)(
                h1c + (size_t)((half * 2 + n2) * 8 + kt) * 512 + lane * 8);
          #pragma unroll
          for (int n2 = 0; n2 < 2; ++n2)
            #pragma unroll
            for (int j = 0; j < 2; ++j)
              h2[half * 2 + n2][j] = __builtin_amdgcn_mfma_f32_16x16x32_f16(
                  hac[n2], w2c[j],
                  (ch == 0 && kt == 0) ? zero4 : h2[half * 2 + n2][j], 0, 0, 0);
        }
      }

      __syncthreads();   // WAR: h1c reads done before next chunk/expert L1
    }

    // ---- register epilogue: relu(h2+b2).w3h, gate folded, accumulate ------
    // h2[nt][j][r] = h2[tok=nt*16+q*4+r][h2col=(2w+j)*16+l16]
    float b2v[2], w3v[2];
    #pragma unroll
    for (int j = 0; j < 2; ++j) {
      int n = (w * 2 + j) * 16 + l16;
      b2v[j] = b2[e * H2D + n];
      w3v[j] = w3h[e * H2D + n];
    }
    #pragma unroll
    for (int nt = 0; nt < 4; ++nt) {
      #pragma unroll
      for (int r = 0; r < 4; ++r) {
        float s = 0.f;
        #pragma unroll
        for (int j = 0; j < 2; ++j)
          s += fmaxf(h2[nt][j][r] + b2v[j], 0.f) * w3v[j];
        yacc[nt][r] += g_lds[(nt * 16 + q * 4 + r) * 17 + e] * s;
      }
    }
  }

  // ---- final reduction: sum yacc over the 16 l16-lanes (h2col within
  //      tile), then over the 8 waves via fin[8][TK] -----------------------
  #pragma unroll
  for (int nt = 0; nt < 4; ++nt) {
    #pragma unroll
    for (int r = 0; r < 4; ++r) {
      float v = yacc[nt][r];
      v += __shfl_xor(v, 1);
      v += __shfl_xor(v, 2);
      v += __shfl_xor(v, 4);
      v += __shfl_xor(v, 8);
      yacc[nt][r] = v;
    }
  }
  if (l16 == 0) {
    #pragma unroll
    for (int nt = 0; nt < 4; ++nt)
      #pragma unroll
      for (int r = 0; r < 4; ++r)
        fin[w * TK + nt * 16 + q * 4 + r] = yacc[nt][r];
  }
  __syncthreads();
  if (tid < TK) {
    float sum = 0.f;
    #pragma unroll
    for (int k = 0; k < 8; ++k) sum += fin[k * TK + tid];
    float gc = 0.f;
    #pragma unroll
    for (int e = 0; e < NE; ++e) gc += g_lds[tid * 17 + e] * c3[e];
    out[m0 + tid] = sum + gc + head_b[0];
  }
}

// ---------------------------------------------------------------------------
extern "C" void kernel_launch(void* const* d_in, const int* in_sizes, int n_in,
                              void* d_out, int out_size, void* d_ws, size_t ws_size,
                              hipStream_t stream) {
  const float* x      = (const float*)d_in[0];
  const float* gate_w = (const float*)d_in[1];
  const float* gate_b = (const float*)d_in[2];
  const float* W1     = (const float*)d_in[3];
  const float* b1     = (const float*)d_in[4];
  const float* W2     = (const float*)d_in[5];
  const float* b2     = (const float*)d_in[6];
  const float* W3     = (const float*)d_in[7];
  const float* b3     = (const float*)d_in[8];
  const float* head_w = (const float*)d_in[9];
  const float* head_b = (const float*)d_in[10];
  float* out = (float*)d_out;

  // workspace layout (16B-aligned)
  char* ws = (char*)d_ws;
  _Float16* w1p = (_Float16*)(ws);                 // 4,194,304 B
  _Float16* w2p = (_Float16*)(ws + 4194304);       // 4,194,304 B
  _Float16* gwp = (_Float16*)(ws + 8388608);       // 8,192 B
  float*    w3h = (float*)(ws + 8396800);          // 16,384 B
  float*    c3  = (float*)(ws + 8413184);          // 64 B

  hipLaunchKernelGGL(prep_kernel, dim3(402), dim3(256), 0, stream,
                     W1, W2, W3, b3, head_w, gate_w, w1p, w2p, w3h, c3, gwp);
  hipLaunchKernelGGL(moe_main, dim3(B_TOK / TK), dim3(512), 0, stream,
                     x, b1, b2, w1p, w2p, gwp, gate_b, w3h, c3, head_b, out);
}